// Round 2
// baseline (3186.792 us; speedup 1.0000x reference)
//
#include <hip/hip_runtime.h>

#define TT 256
#define BB 32
#define HH 512
#define EE 512
#define GG 2048
#define MM 8192
#define CC 9
#define NWG 8   // workgroups per direction in lstm_rec

typedef __attribute__((ext_vector_type(8))) short bf16x8;
typedef __attribute__((ext_vector_type(4))) float f32x4;
typedef __attribute__((ext_vector_type(4))) unsigned short us4;

__device__ inline float b2f(unsigned short u) {
    union { unsigned int i; float f; } v; v.i = ((unsigned int)u) << 16; return v.f;
}
__device__ inline unsigned short f2b(float f) {
    union { float f; unsigned int i; } v; v.f = f;
    unsigned int x = v.i;
    return (unsigned short)((x + 0x7FFFu + ((x >> 16) & 1u)) >> 16);
}
__device__ inline float sigm(float x) { return 1.f / (1.f + __expf(-x)); }
__device__ inline float tanh_f(float x) {
    float ax = fminf(fabsf(x), 12.f);
    float e = __expf(2.f * ax);
    float r = (e - 1.f) / (e + 1.f);
    return x < 0.f ? -r : r;
}

// ---------------- prep: fp32->bf16 weight conversion + bias sums ----------------
__global__ void prep_k(const float* __restrict__ wihf, const float* __restrict__ whhf,
                       const float* __restrict__ wihb, const float* __restrict__ whhb,
                       const float* __restrict__ bihf, const float* __restrict__ bhhf,
                       const float* __restrict__ bihb, const float* __restrict__ bhhb,
                       unsigned short* __restrict__ wih, unsigned short* __restrict__ whh,
                       float* __restrict__ bias)
{
    int v = blockIdx.x * 256 + threadIdx.x;   // 0..262143, 4 floats each per matrix
    float4 a;
    us4 o;
    a = ((const float4*)wihf)[v];
    o.x = f2b(a.x); o.y = f2b(a.y); o.z = f2b(a.z); o.w = f2b(a.w);
    *(us4*)(wih + (size_t)v * 4) = o;
    a = ((const float4*)whhf)[v];
    o.x = f2b(a.x); o.y = f2b(a.y); o.z = f2b(a.z); o.w = f2b(a.w);
    *(us4*)(whh + (size_t)v * 4) = o;
    a = ((const float4*)wihb)[v];
    o.x = f2b(a.x); o.y = f2b(a.y); o.z = f2b(a.z); o.w = f2b(a.w);
    *(us4*)(wih + 1048576 + (size_t)v * 4) = o;
    a = ((const float4*)whhb)[v];
    o.x = f2b(a.x); o.y = f2b(a.y); o.z = f2b(a.z); o.w = f2b(a.w);
    *(us4*)(whh + 1048576 + (size_t)v * 4) = o;
    if (v < 2048)      bias[v] = bihf[v] + bhhf[v];
    else if (v < 4096) bias[v] = bihb[v - 2048] + bhhb[v - 2048];
}

// ---------------- embedding lookup -> bf16 x ----------------
__global__ void embed_k(const int* __restrict__ ids, const float* __restrict__ emb,
                        unsigned short* __restrict__ xb)
{
    int v = blockIdx.x * 256 + threadIdx.x;   // 0..1048575 (8192*512/4)
    int row = v >> 7;
    int col4 = (v & 127) * 4;
    int id = ids[row];
    float4 e;
    if (id != 0) e = *(const float4*)(emb + (size_t)id * 512 + col4);
    else { e.x = 0.f; e.y = 0.f; e.z = 0.f; e.w = 0.f; }
    us4 o; o.x = f2b(e.x); o.y = f2b(e.y); o.z = f2b(e.z); o.w = f2b(e.w);
    *(us4*)(xb + (size_t)row * 512 + col4) = o;
}

// ---------------- input GEMM: xp = x @ w_ih^T + bias ----------------
__global__ __launch_bounds__(256) void gemm_xp(const unsigned short* __restrict__ x,
                                               const unsigned short* __restrict__ w,
                                               const float* __restrict__ bias,
                                               unsigned short* __restrict__ xp)
{
    __shared__ unsigned short As[128 * 64];
    __shared__ unsigned short Bs[128 * 64];
    const int tid = threadIdx.x;
    const int wave = tid >> 6, lane = tid & 63;
    const int quad = lane >> 4, r16 = lane & 15;
    const int wm = wave >> 1, wn = wave & 1;
    const int mt0 = blockIdx.x * 128;
    const int nt0 = blockIdx.y * 128;
    const int dir = blockIdx.z;
    const unsigned short* bg = w + (size_t)dir * GG * EE;
    const float* bs = bias + dir * GG;
    unsigned short* out = xp + (size_t)dir * (size_t)MM * GG;

    f32x4 acc[4][4] = {};

    for (int kb = 0; kb < 8; ++kb) {
        const int k0 = kb * 64;
        int4 ar[4], br[4];
#pragma unroll
        for (int c = 0; c < 4; ++c) {
            int seg = c * 256 + tid;
            int row = seg >> 3, ks = seg & 7;
            int kg = ks ^ (row & 7);
            ar[c] = *(const int4*)(x  + (size_t)(mt0 + row) * EE + k0 + kg * 8);
            br[c] = *(const int4*)(bg + (size_t)(nt0 + row) * EE + k0 + kg * 8);
        }
        __syncthreads();
#pragma unroll
        for (int c = 0; c < 4; ++c) {
            int seg = c * 256 + tid;
            *(int4*)&As[seg * 8] = ar[c];
            *(int4*)&Bs[seg * 8] = br[c];
        }
        __syncthreads();
#pragma unroll
        for (int ck = 0; ck < 2; ++ck) {
            bf16x8 afr[4], bfr[4];
#pragma unroll
            for (int mt = 0; mt < 4; ++mt) {
                int row = wm * 64 + mt * 16 + r16;
                int kp = (ck * 4 + quad) ^ (row & 7);
                afr[mt] = *(const bf16x8*)&As[row * 64 + kp * 8];
            }
#pragma unroll
            for (int nt = 0; nt < 4; ++nt) {
                int row = wn * 64 + nt * 16 + r16;
                int kp = (ck * 4 + quad) ^ (row & 7);
                bfr[nt] = *(const bf16x8*)&Bs[row * 64 + kp * 8];
            }
#pragma unroll
            for (int mt = 0; mt < 4; ++mt)
#pragma unroll
                for (int nt = 0; nt < 4; ++nt)
                    acc[mt][nt] = __builtin_amdgcn_mfma_f32_16x16x32_bf16(afr[mt], bfr[nt], acc[mt][nt], 0, 0, 0);
        }
    }
#pragma unroll
    for (int nt = 0; nt < 4; ++nt) {
        int col = nt0 + wn * 64 + nt * 16 + r16;
        float bv = bs[col];
#pragma unroll
        for (int mt = 0; mt < 4; ++mt) {
            int rbase = mt0 + wm * 64 + mt * 16 + quad * 4;
#pragma unroll
            for (int r = 0; r < 4; ++r)
                out[(size_t)(rbase + r) * GG + col] = f2b(acc[mt][nt][r] + bv);
        }
    }
}

// ---------------- persistent bidirectional LSTM recurrence ----------------
// grid 16 (cooperative): dir = bx>>3, wg = bx&7 owns hidden units [wg*64, wg*64+64)
// 1024 threads = 16 waves; wave w: gate = w>>2, n-subtile = w&3 (16 units)
// h handoff: relaxed agent-scope atomics (LLC-coherent, no cache flushes);
// per-WG flag slot, release-store (no RMW contention).
__global__ __launch_bounds__(1024, 4) void lstm_rec(const unsigned short* __restrict__ whh,
                                                    const unsigned short* __restrict__ xp,
                                                    unsigned short* __restrict__ h_all,
                                                    unsigned int* __restrict__ cnt)
{
    __shared__ union {
        unsigned short hb[32][520];   // h_{t-1} staging (stride 520: b128-clean)
        float gb[4][32][64];          // gate pre-activations (aliased; barrier-separated)
    } sm;

    const int bx = blockIdx.x;
    const int dir = bx >> 3;
    const int wg = bx & 7;
    const int js = wg * 64;
    const int tid = threadIdx.x;
    const int wave = tid >> 6, lane = tid & 63;
    const int quad = lane >> 4, r16 = lane & 15;
    const int g = wave >> 2, nt = wave & 3;
    const int wcol = g * 512 + js + nt * 16 + r16;   // gate-row in whh / col in xp

    // B-operand fragments of this WG's w_hh slice, in registers (64 VGPRs)
    bf16x8 wfr[16];
    {
        const unsigned short* wrow = whh + (size_t)dir * GG * HH + (size_t)wcol * 512;
#pragma unroll
        for (int kc = 0; kc < 16; ++kc)
            wfr[kc] = *(const bf16x8*)(wrow + kc * 32 + quad * 8);
    }

    // cell state in registers: thread owns (b = tid>>5, j = js + 2*(tid&31) + {0,1})
    const int cb = tid >> 5, cj = (tid & 31) * 2;
    float cr0 = 0.f, cr1 = 0.f;

    unsigned short* hd = h_all + (size_t)dir * TT * BB * HH;
    const unsigned short* xpd = xp + (size_t)dir * (size_t)MM * GG;
    unsigned int* flg = cnt + dir * NWG;

    for (int t = 0; t < TT; ++t) {
        const int te = dir ? (TT - 1 - t) : t;
        // prefetch xp for this step (independent of recurrence; in flight during poll)
        float xv[8];
#pragma unroll
        for (int r = 0; r < 4; ++r) {
            int blo = quad * 4 + r;
            xv[r]     = b2f(xpd[(size_t)(blo * TT + te) * GG + wcol]);
            xv[4 + r] = b2f(xpd[(size_t)((blo + 16) * TT + te) * GG + wcol]);
        }

        if (t == 0) {
            // zero hbuf
            for (int v = tid; v < 4096; v += 1024) {
                int b = v >> 7, wi = v & 127;
                *(unsigned long long*)&sm.hb[b][wi * 4] = 0ull;
            }
            __syncthreads();
        } else {
            if (wave == 0) {
                const unsigned int tgt = (unsigned int)t;
                for (;;) {
                    unsigned int f = tgt;
                    if (lane < NWG)
                        f = __hip_atomic_load(&flg[lane], __ATOMIC_RELAXED, __HIP_MEMORY_SCOPE_AGENT);
                    unsigned long long bal = __ballot(f >= tgt);
                    if (bal == ~0ull) break;
                    __builtin_amdgcn_s_sleep(1);
                }
            }
            __syncthreads();
            const int tp = dir ? (te + 1) : (te - 1);
            const unsigned long long* hsrc = (const unsigned long long*)(hd + (size_t)tp * BB * HH);
#pragma unroll
            for (int i = 0; i < 4; ++i) {
                int v = tid + i * 1024;
                int b = v >> 7, wi = v & 127;
                unsigned long long hv =
                    __hip_atomic_load(&hsrc[v], __ATOMIC_RELAXED, __HIP_MEMORY_SCOPE_AGENT);
                *(unsigned long long*)&sm.hb[b][wi * 4] = hv;
            }
            __syncthreads();
        }

        // gates[b][n] for (gate g, units js+nt*16..+16): two 16-batch M halves
        f32x4 alo = {0.f, 0.f, 0.f, 0.f}, ahi = {0.f, 0.f, 0.f, 0.f};
#pragma unroll
        for (int kc = 0; kc < 16; ++kc) {
            const int ko = kc * 32 + quad * 8;
            bf16x8 aflo = *(const bf16x8*)&sm.hb[r16][ko];
            bf16x8 afhi = *(const bf16x8*)&sm.hb[16 + r16][ko];
            alo = __builtin_amdgcn_mfma_f32_16x16x32_bf16(aflo, wfr[kc], alo, 0, 0, 0);
            ahi = __builtin_amdgcn_mfma_f32_16x16x32_bf16(afhi, wfr[kc], ahi, 0, 0, 0);
        }
        __syncthreads();   // all hbuf reads done before gbuf overwrites (union)
#pragma unroll
        for (int r = 0; r < 4; ++r) {
            sm.gb[g][quad * 4 + r][nt * 16 + r16]      = alo[r] + xv[r];
            sm.gb[g][16 + quad * 4 + r][nt * 16 + r16] = ahi[r] + xv[4 + r];
        }
        __syncthreads();

        // nonlinearity: thread owns (cb, cj) and (cb, cj+1)
        {
            float2 iv = *(const float2*)&sm.gb[0][cb][cj];
            float2 fv = *(const float2*)&sm.gb[1][cb][cj];
            float2 gv = *(const float2*)&sm.gb[2][cb][cj];
            float2 ov = *(const float2*)&sm.gb[3][cb][cj];
            cr0 = sigm(fv.x) * cr0 + sigm(iv.x) * tanh_f(gv.x);
            cr1 = sigm(fv.y) * cr1 + sigm(iv.y) * tanh_f(gv.y);
            float h0 = sigm(ov.x) * tanh_f(cr0);
            float h1 = sigm(ov.y) * tanh_f(cr1);
            unsigned int packed = (unsigned int)f2b(h0) | ((unsigned int)f2b(h1) << 16);
            unsigned int* hp = (unsigned int*)(hd + (size_t)te * BB * HH + cb * 512 + js + cj);
            __hip_atomic_store(hp, packed, __ATOMIC_RELAXED, __HIP_MEMORY_SCOPE_AGENT);
        }
        __syncthreads();   // drains vmcnt: all waves' h stores acked before flag
        if (tid == 0)
            __hip_atomic_store(&flg[wg], (unsigned int)(t + 1),
                               __ATOMIC_RELEASE, __HIP_MEMORY_SCOPE_AGENT);
    }
}

// ---------------- classifier: logits = [hf|hb] @ cls_w^T + cls_b ----------------
__global__ __launch_bounds__(256) void logits_k(const unsigned short* __restrict__ h_all,
                                                const float* __restrict__ clsw,
                                                const float* __restrict__ clsb,
                                                float* __restrict__ logits)
{
    const int tid = threadIdx.x;
    const int wave = tid >> 6, lane = tid & 63;
    const int wgid = blockIdx.x * 4 + wave;    // 0..1023

    unsigned int wreg[9][8];
#pragma unroll
    for (int c = 0; c < 9; ++c)
#pragma unroll
        for (int q = 0; q < 8; ++q) {
            float w0 = clsw[c * 1024 + (2 * q) * 64 + lane];
            float w1 = clsw[c * 1024 + (2 * q + 1) * 64 + lane];
            wreg[c][q] = (unsigned int)f2b(w0) | ((unsigned int)f2b(w1) << 16);
        }

    const unsigned short* hfb = h_all;
    const unsigned short* hbb = h_all + (size_t)TT * BB * HH;

    for (int i = 0; i < 8; ++i) {
        int m = wgid * 8 + i;                  // m = b*256 + t
        int b = m >> 8, t = m & 255;
        const unsigned short* hf = hfb + ((size_t)t * BB + b) * HH;
        const unsigned short* hb = hbb + ((size_t)t * BB + b) * HH;
        float acc[9];
#pragma unroll
        for (int c = 0; c < 9; ++c) acc[c] = 0.f;
#pragma unroll
        for (int u = 0; u < 16; ++u) {
            const unsigned short* src = (u < 8) ? (hf + u * 64) : (hb + (u - 8) * 64);
            float hv = b2f(src[lane]);
#pragma unroll
            for (int c = 0; c < 9; ++c) {
                unsigned short wv = (u & 1) ? (unsigned short)(wreg[c][u >> 1] >> 16)
                                            : (unsigned short)(wreg[c][u >> 1] & 0xFFFFu);
                acc[c] += hv * b2f(wv);
            }
        }
#pragma unroll
        for (int c = 0; c < 9; ++c) {
            float s = acc[c];
            for (int off = 32; off > 0; off >>= 1) s += __shfl_down(s, off);
            if (lane == 0) logits[(size_t)m * 9 + c] = s + clsb[c];
        }
    }
}

// ---------------- CRF log-likelihood per sequence ----------------
__global__ void crf_k(const float* __restrict__ logits, const int* __restrict__ label,
                      const float* __restrict__ startp, const float* __restrict__ endp,
                      const float* __restrict__ trans, float* __restrict__ llh)
{
    const int b = blockIdx.x;
    const int lane = threadIdx.x;   // 64
    __shared__ float tr[81];
    __shared__ float alpha[9];
    __shared__ int tags[TT];
    for (int v = lane; v < 81; v += 64) tr[v] = trans[v];
    for (int v = lane; v < TT; v += 64) tags[v] = label[b * TT + v];
    __syncthreads();
    const float* lg = logits + (size_t)b * TT * 9;

    float part = 0.f; int mcnt = 0;
    for (int t = lane; t < TT; t += 64) {
        int tg = tags[t];
        bool m = tg > -1;
        if (m) mcnt++;
        if (t == 0)      part += startp[tg] + lg[tg];
        else if (m)      part += lg[t * 9 + tg] + tr[tags[t - 1] * 9 + tg];
    }
    for (int off = 32; off > 0; off >>= 1) {
        part += __shfl_down(part, off);
        mcnt += __shfl_down(mcnt, off);
    }
    part = __shfl(part, 0);
    mcnt = __shfl(mcnt, 0);
    float num = part + endp[tags[mcnt - 1]];

    if (lane < 9) alpha[lane] = startp[lane] + lg[lane];
    __syncthreads();
    for (int t = 1; t < TT; ++t) {
        float nxt = 0.f;
        if (lane < 9) {
            float mx = -1e30f;
#pragma unroll
            for (int c1 = 0; c1 < 9; ++c1) mx = fmaxf(mx, alpha[c1] + tr[c1 * 9 + lane]);
            float s = 0.f;
#pragma unroll
            for (int c1 = 0; c1 < 9; ++c1) s += __expf(alpha[c1] + tr[c1 * 9 + lane] - mx);
            nxt = mx + __logf(s) + lg[t * 9 + lane];
            if (tags[t] <= -1) nxt = alpha[lane];
        }
        __syncthreads();
        if (lane < 9) alpha[lane] = nxt;
        __syncthreads();
    }
    if (lane == 0) {
        float mx = -1e30f;
#pragma unroll
        for (int c = 0; c < 9; ++c) mx = fmaxf(mx, alpha[c] + endp[c]);
        float s = 0.f;
#pragma unroll
        for (int c = 0; c < 9; ++c) s += __expf(alpha[c] + endp[c] - mx);
        llh[b] = num - (mx + __logf(s));
    }
}

__global__ void fin_k(const float* __restrict__ llh, float* __restrict__ out)
{
    int lane = threadIdx.x;
    float v = (lane < 32) ? llh[lane] : 0.f;
    for (int off = 32; off > 0; off >>= 1) v += __shfl_down(v, off);
    if (lane == 0) out[0] = -v * (1.f / 32.f);
}

// ---------------- launch ----------------
extern "C" void kernel_launch(void* const* d_in, const int* in_sizes, int n_in,
                              void* d_out, int out_size, void* d_ws, size_t ws_size,
                              hipStream_t stream)
{
    const int*   input = (const int*)  d_in[0];
    const int*   label = (const int*)  d_in[1];
    const float* emb   = (const float*)d_in[2];
    const float* wihf  = (const float*)d_in[3];
    const float* whhf  = (const float*)d_in[4];
    const float* bihf  = (const float*)d_in[5];
    const float* bhhf  = (const float*)d_in[6];
    const float* wihb  = (const float*)d_in[7];
    const float* whhb  = (const float*)d_in[8];
    const float* bihb  = (const float*)d_in[9];
    const float* bhhb  = (const float*)d_in[10];
    const float* clsw  = (const float*)d_in[11];
    const float* clsb  = (const float*)d_in[12];
    const float* stp   = (const float*)d_in[13];
    const float* enp   = (const float*)d_in[14];
    const float* trp   = (const float*)d_in[15];

    char* ws = (char*)d_ws;
    unsigned short* xb   = (unsigned short*)(ws + 0);           //  8 MB
    unsigned short* wih  = (unsigned short*)(ws + 8388608);     //  4 MB
    unsigned short* whh  = (unsigned short*)(ws + 12582912);    //  4 MB
    float*          bias = (float*)(ws + 16777216);             // 16 KB
    unsigned short* xp   = (unsigned short*)(ws + 16793600);    // 64 MB
    unsigned short* hall = (unsigned short*)(ws + 83902464);    // 16 MB
    float*          lgt  = (float*)(ws + 100679680);            // 288 KB
    float*          llh  = (float*)(ws + 100974592);            // 128 B
    unsigned int*   cnt  = (unsigned int*)(ws + 100974848);     // flags [2][8]

    hipMemsetAsync(cnt, 0, 256, stream);
    prep_k<<<1024, 256, 0, stream>>>(wihf, whhf, wihb, whhb, bihf, bhhf, bihb, bhhb, wih, whh, bias);
    embed_k<<<4096, 256, 0, stream>>>(input, emb, xb);
    gemm_xp<<<dim3(64, 16, 2), 256, 0, stream>>>(xb, wih, bias, xp);
    {
        const unsigned short* a0 = whh;
        const unsigned short* a1 = xp;
        unsigned short* a2 = hall;
        unsigned int* a3 = cnt;
        void* args[] = { &a0, &a1, &a2, &a3 };
        hipLaunchCooperativeKernel((const void*)lstm_rec, dim3(2 * NWG), dim3(1024), args, 0, stream);
    }
    logits_k<<<256, 256, 0, stream>>>(hall, clsw, clsb, lgt);
    crf_k<<<32, 64, 0, stream>>>(lgt, label, stp, enp, trp, llh);
    fin_k<<<1, 64, 0, stream>>>(llh, (float*)d_out);
}

// Round 3
// 1193.233 us; speedup vs baseline: 2.6707x; 2.6707x over previous
//
#include <hip/hip_runtime.h>

#define TT 256
#define BB 32
#define HH 512
#define EE 512
#define GG 2048
#define MM 8192
#define CC 9
#define NWG 32   // workgroups per direction in lstm_rec

typedef __attribute__((ext_vector_type(8))) short bf16x8;
typedef __attribute__((ext_vector_type(4))) float f32x4;
typedef __attribute__((ext_vector_type(4))) unsigned short us4;
typedef unsigned long long ull;

__device__ inline float b2f(unsigned short u) {
    union { unsigned int i; float f; } v; v.i = ((unsigned int)u) << 16; return v.f;
}
__device__ inline unsigned short f2b(float f) {
    union { float f; unsigned int i; } v; v.f = f;
    unsigned int x = v.i;
    return (unsigned short)((x + 0x7FFFu + ((x >> 16) & 1u)) >> 16);
}
__device__ inline float sigm(float x) { return 1.f / (1.f + __expf(-x)); }
__device__ inline float tanh_f(float x) {
    float ax = fminf(fabsf(x), 12.f);
    float e = __expf(2.f * ax);
    float r = (e - 1.f) / (e + 1.f);
    return x < 0.f ? -r : r;
}

// ---------------- prep: fp32->bf16 weight conversion + bias sums ----------------
__global__ void prep_k(const float* __restrict__ wihf, const float* __restrict__ whhf,
                       const float* __restrict__ wihb, const float* __restrict__ whhb,
                       const float* __restrict__ bihf, const float* __restrict__ bhhf,
                       const float* __restrict__ bihb, const float* __restrict__ bhhb,
                       unsigned short* __restrict__ wih, unsigned short* __restrict__ whh,
                       float* __restrict__ bias)
{
    int v = blockIdx.x * 256 + threadIdx.x;   // 0..262143, 4 floats each per matrix
    float4 a;
    us4 o;
    a = ((const float4*)wihf)[v];
    o.x = f2b(a.x); o.y = f2b(a.y); o.z = f2b(a.z); o.w = f2b(a.w);
    *(us4*)(wih + (size_t)v * 4) = o;
    a = ((const float4*)whhf)[v];
    o.x = f2b(a.x); o.y = f2b(a.y); o.z = f2b(a.z); o.w = f2b(a.w);
    *(us4*)(whh + (size_t)v * 4) = o;
    a = ((const float4*)wihb)[v];
    o.x = f2b(a.x); o.y = f2b(a.y); o.z = f2b(a.z); o.w = f2b(a.w);
    *(us4*)(wih + 1048576 + (size_t)v * 4) = o;
    a = ((const float4*)whhb)[v];
    o.x = f2b(a.x); o.y = f2b(a.y); o.z = f2b(a.z); o.w = f2b(a.w);
    *(us4*)(whh + 1048576 + (size_t)v * 4) = o;
    if (v < 2048)      bias[v] = bihf[v] + bhhf[v];
    else if (v < 4096) bias[v] = bihb[v - 2048] + bhhb[v - 2048];
}

// ---------------- embedding lookup -> bf16 x ----------------
__global__ void embed_k(const int* __restrict__ ids, const float* __restrict__ emb,
                        unsigned short* __restrict__ xb)
{
    int v = blockIdx.x * 256 + threadIdx.x;   // 0..1048575 (8192*512/4)
    int row = v >> 7;
    int col4 = (v & 127) * 4;
    int id = ids[row];
    float4 e;
    if (id != 0) e = *(const float4*)(emb + (size_t)id * 512 + col4);
    else { e.x = 0.f; e.y = 0.f; e.z = 0.f; e.w = 0.f; }
    us4 o; o.x = f2b(e.x); o.y = f2b(e.y); o.z = f2b(e.z); o.w = f2b(e.w);
    *(us4*)(xb + (size_t)row * 512 + col4) = o;
}

// ---------------- input GEMM: xp = x @ w_ih^T + bias ----------------
__global__ __launch_bounds__(256) void gemm_xp(const unsigned short* __restrict__ x,
                                               const unsigned short* __restrict__ w,
                                               const float* __restrict__ bias,
                                               unsigned short* __restrict__ xp)
{
    __shared__ unsigned short As[128 * 64];
    __shared__ unsigned short Bs[128 * 64];
    const int tid = threadIdx.x;
    const int wave = tid >> 6, lane = tid & 63;
    const int quad = lane >> 4, r16 = lane & 15;
    const int wm = wave >> 1, wn = wave & 1;
    const int mt0 = blockIdx.x * 128;
    const int nt0 = blockIdx.y * 128;
    const int dir = blockIdx.z;
    const unsigned short* bg = w + (size_t)dir * GG * EE;
    const float* bs = bias + dir * GG;
    unsigned short* out = xp + (size_t)dir * (size_t)MM * GG;

    f32x4 acc[4][4] = {};

    for (int kb = 0; kb < 8; ++kb) {
        const int k0 = kb * 64;
        int4 ar[4], br[4];
#pragma unroll
        for (int c = 0; c < 4; ++c) {
            int seg = c * 256 + tid;
            int row = seg >> 3, ks = seg & 7;
            int kg = ks ^ (row & 7);
            ar[c] = *(const int4*)(x  + (size_t)(mt0 + row) * EE + k0 + kg * 8);
            br[c] = *(const int4*)(bg + (size_t)(nt0 + row) * EE + k0 + kg * 8);
        }
        __syncthreads();
#pragma unroll
        for (int c = 0; c < 4; ++c) {
            int seg = c * 256 + tid;
            *(int4*)&As[seg * 8] = ar[c];
            *(int4*)&Bs[seg * 8] = br[c];
        }
        __syncthreads();
#pragma unroll
        for (int ck = 0; ck < 2; ++ck) {
            bf16x8 afr[4], bfr[4];
#pragma unroll
            for (int mt = 0; mt < 4; ++mt) {
                int row = wm * 64 + mt * 16 + r16;
                int kp = (ck * 4 + quad) ^ (row & 7);
                afr[mt] = *(const bf16x8*)&As[row * 64 + kp * 8];
            }
#pragma unroll
            for (int nt = 0; nt < 4; ++nt) {
                int row = wn * 64 + nt * 16 + r16;
                int kp = (ck * 4 + quad) ^ (row & 7);
                bfr[nt] = *(const bf16x8*)&Bs[row * 64 + kp * 8];
            }
#pragma unroll
            for (int mt = 0; mt < 4; ++mt)
#pragma unroll
                for (int nt = 0; nt < 4; ++nt)
                    acc[mt][nt] = __builtin_amdgcn_mfma_f32_16x16x32_bf16(afr[mt], bfr[nt], acc[mt][nt], 0, 0, 0);
        }
    }
#pragma unroll
    for (int nt = 0; nt < 4; ++nt) {
        int col = nt0 + wn * 64 + nt * 16 + r16;
        float bv = bs[col];
#pragma unroll
        for (int mt = 0; mt < 4; ++mt) {
            int rbase = mt0 + wm * 64 + mt * 16 + quad * 4;
#pragma unroll
            for (int r = 0; r < 4; ++r)
                out[(size_t)(rbase + r) * GG + col] = f2b(acc[mt][nt][r] + bv);
        }
    }
}

// ---------------- persistent bidirectional LSTM recurrence ----------------
// grid 64 (cooperative): dir = bx>>5, wg = bx&31 owns hidden units [wg*16, wg*16+16)
// 256 threads = 4 waves; wave = gate (i,f,g,o). 1 WG/CU -> LDS pipe unsaturated.
// Handoff: per-WG flag slot (relaxed store after barrier-drained h stores);
// h exchanged via relaxed agent-scope 8B atomics (LLC-coherent, NO cache flushes).
__global__ __launch_bounds__(256) void lstm_rec(const unsigned short* __restrict__ whh,
                                                const unsigned short* __restrict__ xp,
                                                unsigned short* __restrict__ h_all,
                                                unsigned int* __restrict__ cnt)
{
    __shared__ unsigned short hbuf[32][520];   // h_{t-1} staging (stride 520)
    __shared__ float gbuf[4][32][16];          // gate pre-activations

    const int bx = blockIdx.x;
    const int dir = bx >> 5;
    const int wg = bx & 31;
    const int js = wg * 16;
    const int tid = threadIdx.x;
    const int wave = tid >> 6, lane = tid & 63;
    const int quad = lane >> 4, r16 = lane & 15;

    // B-operand fragments of this WG's w_hh slice, in registers (64 VGPRs):
    // lane holds W[gate=wave][hid=js+r16][k = kc*32 + quad*8 + j]
    bf16x8 wfr[16];
    {
        const unsigned short* wrow = whh + (size_t)dir * GG * HH
                                   + (size_t)(wave * 512 + js + r16) * 512;
#pragma unroll
        for (int kc = 0; kc < 16; ++kc)
            wfr[kc] = *(const bf16x8*)(wrow + kc * 32 + quad * 8);
    }

    // cell state in registers: thread owns (b = tid>>3, j = js + 2*(tid&7) + {0,1})
    const int cb = tid >> 3, cj = (tid & 7) * 2;
    float cr0 = 0.f, cr1 = 0.f;

    unsigned short* hd = h_all + (size_t)dir * TT * BB * HH;
    const unsigned short* xpd = xp + (size_t)dir * (size_t)MM * GG;
    unsigned int* flg = cnt + dir * NWG;
    const int col = wave * 512 + js + r16;     // gate-row in whh / col in xp

    for (int t = 0; t < TT; ++t) {
        const int te = dir ? (TT - 1 - t) : t;
        // prefetch xp for this step (independent; in flight during poll)
        float xv[8];
#pragma unroll
        for (int r = 0; r < 4; ++r) {
            int blo = quad * 4 + r;
            xv[r]     = b2f(xpd[(size_t)(blo * TT + te) * GG + col]);
            xv[4 + r] = b2f(xpd[(size_t)((blo + 16) * TT + te) * GG + col]);
        }

        if (t == 0) {
            for (int i = 0; i < 16; ++i) {
                int v = tid + i * 256;
                *(ull*)&hbuf[v >> 7][(v & 127) * 4] = 0ull;
            }
            __syncthreads();
        } else {
            if (wave == 0) {
                const unsigned int tgt = (unsigned int)t;
                for (;;) {
                    unsigned int f = tgt;
                    if (lane < NWG)
                        f = __hip_atomic_load(&flg[lane], __ATOMIC_RELAXED, __HIP_MEMORY_SCOPE_AGENT);
                    if (__ballot(f >= tgt) == ~0ull) break;
                }
            }
            __syncthreads();
            const int tp = dir ? (te + 1) : (te - 1);
            const ull* hsrc = (const ull*)(hd + (size_t)tp * BB * HH);
            ull hv[16];
#pragma unroll
            for (int i = 0; i < 16; ++i)
                hv[i] = __hip_atomic_load(&hsrc[tid + i * 256], __ATOMIC_RELAXED, __HIP_MEMORY_SCOPE_AGENT);
#pragma unroll
            for (int i = 0; i < 16; ++i) {
                int v = tid + i * 256;
                *(ull*)&hbuf[v >> 7][(v & 127) * 4] = hv[i];
            }
            __syncthreads();
        }

        // gates[b][n] for gate=wave, units js..js+16: two 16-batch M halves
        f32x4 alo = {0.f, 0.f, 0.f, 0.f}, ahi = {0.f, 0.f, 0.f, 0.f};
#pragma unroll
        for (int kc = 0; kc < 16; ++kc) {
            const int ko = kc * 32 + quad * 8;
            bf16x8 aflo = *(const bf16x8*)&hbuf[r16][ko];
            bf16x8 afhi = *(const bf16x8*)&hbuf[16 + r16][ko];
            alo = __builtin_amdgcn_mfma_f32_16x16x32_bf16(aflo, wfr[kc], alo, 0, 0, 0);
            ahi = __builtin_amdgcn_mfma_f32_16x16x32_bf16(afhi, wfr[kc], ahi, 0, 0, 0);
        }
#pragma unroll
        for (int r = 0; r < 4; ++r) {
            gbuf[wave][quad * 4 + r][r16]      = alo[r] + xv[r];
            gbuf[wave][16 + quad * 4 + r][r16] = ahi[r] + xv[4 + r];
        }
        __syncthreads();

        // nonlinearity: thread owns (cb, cj) and (cb, cj+1)
        {
            float2 iv = *(const float2*)&gbuf[0][cb][cj];
            float2 fv = *(const float2*)&gbuf[1][cb][cj];
            float2 gv = *(const float2*)&gbuf[2][cb][cj];
            float2 ov = *(const float2*)&gbuf[3][cb][cj];
            cr0 = sigm(fv.x) * cr0 + sigm(iv.x) * tanh_f(gv.x);
            cr1 = sigm(fv.y) * cr1 + sigm(iv.y) * tanh_f(gv.y);
            float h0 = sigm(ov.x) * tanh_f(cr0);
            float h1 = sigm(ov.y) * tanh_f(cr1);
            unsigned int packed = (unsigned int)f2b(h0) | ((unsigned int)f2b(h1) << 16);
            unsigned int* hp = (unsigned int*)(hd + (size_t)te * BB * HH + cb * 512 + js + cj);
            __hip_atomic_store(hp, packed, __ATOMIC_RELAXED, __HIP_MEMORY_SCOPE_AGENT);
        }
        __syncthreads();   // per-wave vmcnt drained before barrier: all h acked at LLC
        if (tid == 0)
            __hip_atomic_store(&flg[wg], (unsigned int)(t + 1),
                               __ATOMIC_RELAXED, __HIP_MEMORY_SCOPE_AGENT);
    }
}

// ---------------- classifier: logits = [hf|hb] @ cls_w^T + cls_b ----------------
__global__ __launch_bounds__(256) void logits_k(const unsigned short* __restrict__ h_all,
                                                const float* __restrict__ clsw,
                                                const float* __restrict__ clsb,
                                                float* __restrict__ logits)
{
    const int tid = threadIdx.x;
    const int wave = tid >> 6, lane = tid & 63;
    const int wgid = blockIdx.x * 4 + wave;    // 0..1023

    unsigned int wreg[9][8];
#pragma unroll
    for (int c = 0; c < 9; ++c)
#pragma unroll
        for (int q = 0; q < 8; ++q) {
            float w0 = clsw[c * 1024 + (2 * q) * 64 + lane];
            float w1 = clsw[c * 1024 + (2 * q + 1) * 64 + lane];
            wreg[c][q] = (unsigned int)f2b(w0) | ((unsigned int)f2b(w1) << 16);
        }

    const unsigned short* hfb = h_all;
    const unsigned short* hbb = h_all + (size_t)TT * BB * HH;

    for (int i = 0; i < 8; ++i) {
        int m = wgid * 8 + i;                  // m = b*256 + t
        int b = m >> 8, t = m & 255;
        const unsigned short* hf = hfb + ((size_t)t * BB + b) * HH;
        const unsigned short* hb = hbb + ((size_t)t * BB + b) * HH;
        float acc[9];
#pragma unroll
        for (int c = 0; c < 9; ++c) acc[c] = 0.f;
#pragma unroll
        for (int u = 0; u < 16; ++u) {
            const unsigned short* src = (u < 8) ? (hf + u * 64) : (hb + (u - 8) * 64);
            float hv = b2f(src[lane]);
#pragma unroll
            for (int c = 0; c < 9; ++c) {
                unsigned short wv = (u & 1) ? (unsigned short)(wreg[c][u >> 1] >> 16)
                                            : (unsigned short)(wreg[c][u >> 1] & 0xFFFFu);
                acc[c] += hv * b2f(wv);
            }
        }
#pragma unroll
        for (int c = 0; c < 9; ++c) {
            float s = acc[c];
            for (int off = 32; off > 0; off >>= 1) s += __shfl_down(s, off);
            if (lane == 0) logits[(size_t)m * 9 + c] = s + clsb[c];
        }
    }
}

// ---------------- CRF log-likelihood per sequence ----------------
__global__ void crf_k(const float* __restrict__ logits, const int* __restrict__ label,
                      const float* __restrict__ startp, const float* __restrict__ endp,
                      const float* __restrict__ trans, float* __restrict__ llh)
{
    const int b = blockIdx.x;
    const int lane = threadIdx.x;   // 64
    __shared__ float tr[81];
    __shared__ float alpha[9];
    __shared__ int tags[TT];
    for (int v = lane; v < 81; v += 64) tr[v] = trans[v];
    for (int v = lane; v < TT; v += 64) tags[v] = label[b * TT + v];
    __syncthreads();
    const float* lg = logits + (size_t)b * TT * 9;

    float part = 0.f; int mcnt = 0;
    for (int t = lane; t < TT; t += 64) {
        int tg = tags[t];
        bool m = tg > -1;
        if (m) mcnt++;
        if (t == 0)      part += startp[tg] + lg[tg];
        else if (m)      part += lg[t * 9 + tg] + tr[tags[t - 1] * 9 + tg];
    }
    for (int off = 32; off > 0; off >>= 1) {
        part += __shfl_down(part, off);
        mcnt += __shfl_down(mcnt, off);
    }
    part = __shfl(part, 0);
    mcnt = __shfl(mcnt, 0);
    float num = part + endp[tags[mcnt - 1]];

    if (lane < 9) alpha[lane] = startp[lane] + lg[lane];
    __syncthreads();
    for (int t = 1; t < TT; ++t) {
        float nxt = 0.f;
        if (lane < 9) {
            float mx = -1e30f;
#pragma unroll
            for (int c1 = 0; c1 < 9; ++c1) mx = fmaxf(mx, alpha[c1] + tr[c1 * 9 + lane]);
            float s = 0.f;
#pragma unroll
            for (int c1 = 0; c1 < 9; ++c1) s += __expf(alpha[c1] + tr[c1 * 9 + lane] - mx);
            nxt = mx + __logf(s) + lg[t * 9 + lane];
            if (tags[t] <= -1) nxt = alpha[lane];
        }
        __syncthreads();
        if (lane < 9) alpha[lane] = nxt;
        __syncthreads();
    }
    if (lane == 0) {
        float mx = -1e30f;
#pragma unroll
        for (int c = 0; c < 9; ++c) mx = fmaxf(mx, alpha[c] + endp[c]);
        float s = 0.f;
#pragma unroll
        for (int c = 0; c < 9; ++c) s += __expf(alpha[c] + endp[c] - mx);
        llh[b] = num - (mx + __logf(s));
    }
}

__global__ void fin_k(const float* __restrict__ llh, float* __restrict__ out)
{
    int lane = threadIdx.x;
    float v = (lane < 32) ? llh[lane] : 0.f;
    for (int off = 32; off > 0; off >>= 1) v += __shfl_down(v, off);
    if (lane == 0) out[0] = -v * (1.f / 32.f);
}

// ---------------- launch ----------------
extern "C" void kernel_launch(void* const* d_in, const int* in_sizes, int n_in,
                              void* d_out, int out_size, void* d_ws, size_t ws_size,
                              hipStream_t stream)
{
    const int*   input = (const int*)  d_in[0];
    const int*   label = (const int*)  d_in[1];
    const float* emb   = (const float*)d_in[2];
    const float* wihf  = (const float*)d_in[3];
    const float* whhf  = (const float*)d_in[4];
    const float* bihf  = (const float*)d_in[5];
    const float* bhhf  = (const float*)d_in[6];
    const float* wihb  = (const float*)d_in[7];
    const float* whhb  = (const float*)d_in[8];
    const float* bihb  = (const float*)d_in[9];
    const float* bhhb  = (const float*)d_in[10];
    const float* clsw  = (const float*)d_in[11];
    const float* clsb  = (const float*)d_in[12];
    const float* stp   = (const float*)d_in[13];
    const float* enp   = (const float*)d_in[14];
    const float* trp   = (const float*)d_in[15];

    char* ws = (char*)d_ws;
    unsigned short* xb   = (unsigned short*)(ws + 0);           //  8 MB
    unsigned short* wih  = (unsigned short*)(ws + 8388608);     //  4 MB
    unsigned short* whh  = (unsigned short*)(ws + 12582912);    //  4 MB
    float*          bias = (float*)(ws + 16777216);             // 16 KB
    unsigned short* xp   = (unsigned short*)(ws + 16793600);    // 64 MB
    unsigned short* hall = (unsigned short*)(ws + 83902464);    // 16 MB
    float*          lgt  = (float*)(ws + 100679680);            // 288 KB
    float*          llh  = (float*)(ws + 100974592);            // 128 B
    unsigned int*   cnt  = (unsigned int*)(ws + 100974848);     // flags [2][32]

    hipMemsetAsync(cnt, 0, 256, stream);
    prep_k<<<1024, 256, 0, stream>>>(wihf, whhf, wihb, whhb, bihf, bhhf, bihb, bhhb, wih, whh, bias);
    embed_k<<<4096, 256, 0, stream>>>(input, emb, xb);
    gemm_xp<<<dim3(64, 16, 2), 256, 0, stream>>>(xb, wih, bias, xp);
    {
        const unsigned short* a0 = whh;
        const unsigned short* a1 = xp;
        unsigned short* a2 = hall;
        unsigned int* a3 = cnt;
        void* args[] = { &a0, &a1, &a2, &a3 };
        hipLaunchCooperativeKernel((const void*)lstm_rec, dim3(2 * NWG), dim3(256), args, 0, stream);
    }
    logits_k<<<256, 256, 0, stream>>>(hall, clsw, clsb, lgt);
    crf_k<<<32, 64, 0, stream>>>(lgt, label, stp, enp, trp, llh);
    fin_k<<<1, 64, 0, stream>>>(llh, (float*)d_out);
}